// Round 3
// baseline (844.020 us; speedup 1.0000x reference)
//
#include <hip/hip_runtime.h>
#include <hip/hip_fp16.h>

#define N_NODES 100000
#define N_EDGES 1600000
#define IN_DIM 128
#define OUT_DIM 64

#define PROJ_BLKS 1563  // ceil(N_NODES/64): 64 rows per block (4 waves x 16)

// Buckets of 128 nodes: bucket = dst >> 7.
#define NB2 782          // ceil(N_NODES/128); 782*128 = 100096
// Binom(1.6M, 128/1e5): mean 2048, sigma ~45; 2560 = mean + 11 sigma.
#define MAXB2 2560

#define BIN_NBLK 800
#define BIN_CHUNK 2000  // BIN_NBLK * BIN_CHUNK == N_EDGES

#define BG_THREADS 512

typedef short short8 __attribute__((ext_vector_type(8)));
typedef float f32x4 __attribute__((ext_vector_type(4)));

__device__ __forceinline__ short bf16_trunc(float x) {
  return (short)(__float_as_uint(x) >> 16);
}
__device__ __forceinline__ float bf16_tof(short s) {
  return __uint_as_float(((unsigned)(unsigned short)s) << 16);
}
__device__ __forceinline__ float edge_ex(float p) {
  float t2 = __expf(2.f * p);
  float th = 1.f - 2.f * __builtin_amdgcn_rcpf(t2 + 1.f);
  return __expf(th);
}

// ---------------- Kernel 1: MFMA projection ----------------
__global__ __launch_bounds__(256) void fat1_kernel(
    const float* __restrict__ h_init, const float* __restrict__ W1,
    const float* __restrict__ a, float* __restrict__ h,
    __half* __restrict__ h16, float* __restrict__ ha) {
  __shared__ short whi[16 * 64 * 8];  // 16 KB
  __shared__ short wlo[16 * 64 * 8];  // 16 KB

  // stage W as bf16 hi/lo B-fragments (frag f=kc*4+ot, B[k][n]=W1[ot*16+n][k])
  for (int idx = threadIdx.x; idx < 16 * 64; idx += 256) {
    int f = idx >> 6;
    int l = idx & 63;
    int kc = f >> 2, ot = f & 3;
    const float* wsrc =
        W1 + (ot * 16 + (l & 15)) * IN_DIM + kc * 32 + (l >> 4) * 8;
    short hi[8], lo[8];
#pragma unroll
    for (int j = 0; j < 8; j++) {
      float x = wsrc[j];
      short hv = bf16_trunc(x);
      hi[j] = hv;
      lo[j] = bf16_trunc(x - bf16_tof(hv));
    }
    *(short8*)&whi[idx * 8] = *(const short8*)hi;
    *(short8*)&wlo[idx * 8] = *(const short8*)lo;
  }

  int row0 = blockIdx.x * 64;
  int w = threadIdx.x >> 6;
  int l = threadIdx.x & 63;
  int m = l & 15;
  int q = l >> 4;

  int arow = row0 + w * 16 + m;
  if (arow >= N_NODES) arow = N_NODES - 1;
  const float* xsrc = h_init + (size_t)arow * IN_DIM + q * 8;

  short8 ahi[4], alo[4];
#pragma unroll
  for (int kc = 0; kc < 4; kc++) {
    float xv[8];
    *(float4*)&xv[0] = *(const float4*)(xsrc + kc * 32);
    *(float4*)&xv[4] = *(const float4*)(xsrc + kc * 32 + 4);
    short hi[8], lo[8];
#pragma unroll
    for (int j = 0; j < 8; j++) {
      short hv = bf16_trunc(xv[j]);
      hi[j] = hv;
      lo[j] = bf16_trunc(xv[j] - bf16_tof(hv));
    }
    ahi[kc] = *(const short8*)hi;
    alo[kc] = *(const short8*)lo;
  }
  __syncthreads();

  f32x4 acc[4] = {{0.f, 0.f, 0.f, 0.f},
                  {0.f, 0.f, 0.f, 0.f},
                  {0.f, 0.f, 0.f, 0.f},
                  {0.f, 0.f, 0.f, 0.f}};

#pragma unroll
  for (int kc = 0; kc < 4; kc++) {
#pragma unroll
    for (int ot = 0; ot < 4; ot++) {
      int base = (((kc << 2) | ot) * 64 + l) * 8;
      short8 bhi = *(const short8*)&whi[base];
      short8 blo = *(const short8*)&wlo[base];
      acc[ot] = __builtin_amdgcn_mfma_f32_16x16x32_bf16(ahi[kc], bhi, acc[ot],
                                                        0, 0, 0);
      acc[ot] = __builtin_amdgcn_mfma_f32_16x16x32_bf16(ahi[kc], blo, acc[ot],
                                                        0, 0, 0);
      acc[ot] = __builtin_amdgcn_mfma_f32_16x16x32_bf16(alo[kc], bhi, acc[ot],
                                                        0, 0, 0);
    }
  }

  float pa[4] = {0.f, 0.f, 0.f, 0.f};
#pragma unroll
  for (int ot = 0; ot < 4; ot++) {
    float aval = a[ot * 16 + m];
#pragma unroll
    for (int r = 0; r < 4; r++) pa[r] += acc[ot][r] * aval;
  }
  int rowb = row0 + w * 16 + q * 4;
#pragma unroll
  for (int r = 0; r < 4; r++) {
    int row = rowb + r;
    if (row < N_NODES) {
#pragma unroll
      for (int ot = 0; ot < 4; ot++) {
        h[(size_t)row * OUT_DIM + ot * 16 + m] = acc[ot][r];
        h16[(size_t)row * OUT_DIM + ot * 16 + m] = __float2half(acc[ot][r]);
      }
    }
  }
#pragma unroll
  for (int r = 0; r < 4; r++) {
    pa[r] += __shfl_xor(pa[r], 1);
    pa[r] += __shfl_xor(pa[r], 2);
    pa[r] += __shfl_xor(pa[r], 4);
    pa[r] += __shfl_xor(pa[r], 8);
  }
  if (m == 0) {
#pragma unroll
    for (int r = 0; r < 4; r++) {
      int row = rowb + r;
      if (row < N_NODES) ha[row] = pa[r];
    }
  }
}

// ------- Partition into static bucket regions (range reservation) -------
// pairs[pos] = (src << 7) | (dst & 127); region base b*MAXB2 static;
// bucket_cursor holds relative counts (zeroed by hipMemsetAsync).
__global__ __launch_bounds__(256) void bin_scatter_kernel(
    const int* __restrict__ src, const int* __restrict__ dst,
    int* __restrict__ bucket_cursor, unsigned int* __restrict__ pairs) {
  __shared__ int hst[NB2];
  __shared__ int cur[NB2];
  __shared__ int dlds[BIN_CHUNK];  // 8 KB dst cache (avoid 2nd global read)
  int t = threadIdx.x;
  for (int i = t; i < NB2; i += 256) hst[i] = 0;
  __syncthreads();
  int beg = blockIdx.x * BIN_CHUNK;
  for (int e = t; e < BIN_CHUNK; e += 256) {
    int d = dst[beg + e];
    dlds[e] = d;
    atomicAdd(&hst[d >> 7], 1);
  }
  __syncthreads();
  for (int i = t; i < NB2; i += 256) {
    int c = hst[i];
    cur[i] = (c > 0) ? atomicAdd(&bucket_cursor[i], c) + i * MAXB2 : 0;
  }
  __syncthreads();
  for (int e = t; e < BIN_CHUNK; e += 256) {
    int d = dlds[e];
    int pos = atomicAdd(&cur[d >> 7], 1);
    pairs[pos] = ((unsigned int)src[beg + e] << 7) | (unsigned int)(d & 127);
  }
}

// ------- Fused sort+gather: LDS fp32 atomic accumulation per bucket -------
// One block per 128-node bucket. For each edge: ex = edge_ex(ha[d]-ha[s]);
// acc[d][:] += ex * h16[s][:] via ds_add_f32; epilogue relu(2h - acc/den).
// Edge work: 8-lane subgroup per edge (16 B fp16 per lane), unroll 4 for MLP.
__global__ __launch_bounds__(BG_THREADS) void bucket_gather_kernel(
    const float* __restrict__ h, const __half* __restrict__ h16,
    const float* __restrict__ ha, const int* __restrict__ bucket_cursor,
    const unsigned int* __restrict__ pairs, float* __restrict__ out) {
  __shared__ float acc[128 * 66];  // pad 66: ds_add banks <= 4-way
  __shared__ float den[128];
  __shared__ float had[128];
  __shared__ unsigned int plds[MAXB2];
  int b = blockIdx.x;
  int t = threadIdx.x;
  int node0 = b << 7;
  int cnt = bucket_cursor[b];
  if (cnt > MAXB2) cnt = MAXB2;

  for (int i = t; i < cnt; i += BG_THREADS)
    plds[i] = pairs[(size_t)b * MAXB2 + i];
  for (int i = t; i < 128 * 66; i += BG_THREADS) acc[i] = 0.f;
  if (t < 128) {
    int node = node0 + t;
    had[t] = (node < N_NODES) ? ha[node] : 0.f;
    den[t] = 0.f;
  }
  __syncthreads();

  int l = t & 63;
  int g = l >> 3;   // subgroup 0..7 within wave
  int l8 = l & 7;   // 8 lanes x 8 dims
  int slot = (t >> 6) * 8 + g;  // 0..63 subgroup slots per block
  const char* h16b = (const char*)h16;
  int last = cnt - 1;

  for (int i0 = slot * 4; i0 < cnt; i0 += 64 * 4) {
    unsigned int p0 = plds[min(i0 + 0, last)];
    unsigned int p1 = plds[min(i0 + 1, last)];
    unsigned int p2 = plds[min(i0 + 2, last)];
    unsigned int p3 = plds[min(i0 + 3, last)];
    int s0 = p0 >> 7, s1 = p1 >> 7, s2 = p2 >> 7, s3 = p3 >> 7;
    // issue all global loads first (4-deep MLP)
    float hs0 = ha[s0], hs1 = ha[s1], hs2 = ha[s2], hs3 = ha[s3];
    uint4 u0 = *(const uint4*)(h16b + ((size_t)s0 << 7) + (l8 << 4));
    uint4 u1 = *(const uint4*)(h16b + ((size_t)s1 << 7) + (l8 << 4));
    uint4 u2 = *(const uint4*)(h16b + ((size_t)s2 << 7) + (l8 << 4));
    uint4 u3 = *(const uint4*)(h16b + ((size_t)s3 << 7) + (l8 << 4));

#define BG_PROC(K, PK, UK, HSK)                                        \
  {                                                                    \
    int nl = (int)(PK & 127u);                                         \
    float ex = (i0 + K <= last) ? edge_ex(had[nl] - HSK) : 0.f;        \
    union {                                                            \
      uint4 u;                                                         \
      __half hh[8];                                                    \
    } U;                                                               \
    U.u = UK;                                                          \
    float* arow = &acc[nl * 66 + l8 * 8];                              \
    _Pragma("unroll") for (int j = 0; j < 8; j++)                      \
        atomicAdd(&arow[j], __half2float(U.hh[j]) * ex);               \
    if (l8 == 0) atomicAdd(&den[nl], ex);                              \
  }
    BG_PROC(0, p0, u0, hs0)
    BG_PROC(1, p1, u1, hs1)
    BG_PROC(2, p2, u2, hs2)
    BG_PROC(3, p3, u3, hs3)
#undef BG_PROC
  }
  __syncthreads();

  // epilogue: 4 threads per node, 16 dims each; coalesced h read / out write
  int n = t >> 2;
  int q = t & 3;
  int node = node0 + n;
  if (node < N_NODES) {
    float dv = den[n];
    bool has = dv > 0.f;
    float inv = has ? __builtin_amdgcn_rcpf(dv) : 0.f;
    const float* arow = &acc[n * 66 + q * 16];
    const float* hrow = &h[(size_t)node * OUT_DIM + q * 16];
    float* orow = &out[(size_t)node * OUT_DIM + q * 16];
#pragma unroll
    for (int j = 0; j < 16; j++) {
      float hv = hrow[j];
      orow[j] = fmaxf(has ? 2.f * hv - arow[j] * inv : hv, 0.f);
    }
  }
}

extern "C" void kernel_launch(void* const* d_in, const int* in_sizes, int n_in,
                              void* d_out, int out_size, void* d_ws,
                              size_t ws_size, hipStream_t stream) {
  const float* h_init = (const float*)d_in[0];
  const float* W1 = (const float*)d_in[1];
  const float* a = (const float*)d_in[2];
  const int* src = (const int*)d_in[3];
  const int* dst = (const int*)d_in[4];
  float* out = (float*)d_out;

  // workspace layout (~47 MB)
  float* h = (float*)d_ws;                                  // 6.4M floats
  __half* h16 = (__half*)(h + (size_t)N_NODES * OUT_DIM);   // 6.4M halfs
  float* ha = (float*)(h16 + (size_t)N_NODES * OUT_DIM);    // 100K floats
  unsigned int* pairs = (unsigned int*)(ha + N_NODES);      // NB2*MAXB2 u32
  int* bucket_cursor = (int*)(pairs + (size_t)NB2 * MAXB2); // 782

  hipMemsetAsync(bucket_cursor, 0, NB2 * sizeof(int), stream);
  bin_scatter_kernel<<<BIN_NBLK, 256, 0, stream>>>(src, dst, bucket_cursor,
                                                   pairs);
  fat1_kernel<<<PROJ_BLKS, 256, 0, stream>>>(h_init, W1, a, h, h16, ha);
  bucket_gather_kernel<<<NB2, BG_THREADS, 0, stream>>>(h, h16, ha,
                                                       bucket_cursor, pairs,
                                                       out);
}

// Round 4
// 214.941 us; speedup vs baseline: 3.9268x; 3.9268x over previous
//
#include <hip/hip_runtime.h>
#include <hip/hip_fp16.h>

#define N_NODES 100000
#define N_EDGES 1600000
#define IN_DIM 128
#define OUT_DIM 64

#define NBUCK 391       // ceil(N_NODES/256); bucket = dst >> 8
#define MAXB 4608       // Binom(1.6M,256/1e5): mean 4096 + 8 sigma
#define CUR_STRIDE 16   // one cursor per 64B line (kill cross-XCD false sharing)

#define BIN_NBLK 250
#define BIN_CHUNK 6400  // BIN_NBLK * BIN_CHUNK == N_EDGES

#define PROJ_BLKS 1563  // ceil(N_NODES/64): 64 rows per block (4 waves x 16)
#define PB_GRID (PROJ_BLKS + BIN_NBLK)  // 1813, interleaved by %7

#define SG_THREADS 1024

typedef short short8 __attribute__((ext_vector_type(8)));
typedef float f32x4 __attribute__((ext_vector_type(4)));

__device__ __forceinline__ short bf16_trunc(float x) {
  return (short)(__float_as_uint(x) >> 16);
}
__device__ __forceinline__ float bf16_tof(short s) {
  return __uint_as_float(((unsigned)(unsigned short)s) << 16);
}
__device__ __forceinline__ float edge_ex(float p) {
  float t2 = __expf(2.f * p);
  float th = 1.f - 2.f * __builtin_amdgcn_rcpf(t2 + 1.f);
  return __expf(th);
}

// ---- Fused: MFMA projection + bin-scatter, interleaved for co-residency ----
// Every 7th block (r7==3, q7<250) is a bin block: 250 bin + 1563 proj = 1813.
// Bin's latency-bound scattered work hides under proj's MFMA/stream phase.
__global__ __launch_bounds__(256) void fused_pb_kernel(
    const float* __restrict__ h_init, const float* __restrict__ W1,
    const float* __restrict__ a, const int* __restrict__ src,
    const int* __restrict__ dst, float* __restrict__ h,
    __half* __restrict__ h16, float* __restrict__ ha,
    int* __restrict__ bucket_cursor, unsigned int* __restrict__ pairs) {
  __shared__ __align__(16) char smem[16 * 64 * 8 * 2 * sizeof(short)];  // 32KB

  int idx = blockIdx.x;
  int q7 = idx / 7, r7 = idx % 7;
  if (r7 == 3 && q7 < BIN_NBLK) {
    // ---------------- bin-scatter branch (R0-verified structure) ----------
    int* hst = (int*)smem;
    int* cur = hst + NBUCK;
    for (int i = threadIdx.x; i < NBUCK; i += 256) hst[i] = 0;
    __syncthreads();
    int beg = q7 * BIN_CHUNK;
    int end = beg + BIN_CHUNK;
    for (int e = beg + threadIdx.x; e < end; e += 256)
      atomicAdd(&hst[dst[e] >> 8], 1);
    __syncthreads();
    for (int i = threadIdx.x; i < NBUCK; i += 256) {
      int c = hst[i];
      // relative reservation in padded cursor; region base static (i*MAXB)
      cur[i] = (c > 0) ? atomicAdd(&bucket_cursor[i * CUR_STRIDE], c) + i * MAXB
                       : 0;
    }
    __syncthreads();
    for (int e = beg + threadIdx.x; e < end; e += 256) {
      int d = dst[e];
      int pos = atomicAdd(&cur[d >> 8], 1);
      pairs[pos] = ((unsigned int)src[e] << 8) | (unsigned int)(d & 255);
    }
    return;
  }

  // ---------------- projection branch ----------------
  int pb = idx - min(q7 + (r7 > 3 ? 1 : 0), BIN_NBLK);  // proj_id 0..1562
  short* whi = (short*)smem;      // 16*64*8 shorts
  short* wlo = whi + 16 * 64 * 8;

  // stage W as bf16 hi/lo B-fragments (frag f=kc*4+ot, B[k][n]=W1[ot*16+n][k])
  for (int i2 = threadIdx.x; i2 < 16 * 64; i2 += 256) {
    int f = i2 >> 6;
    int l = i2 & 63;
    int kc = f >> 2, ot = f & 3;
    const float* wsrc =
        W1 + (ot * 16 + (l & 15)) * IN_DIM + kc * 32 + (l >> 4) * 8;
    short hi[8], lo[8];
#pragma unroll
    for (int j = 0; j < 8; j++) {
      float x = wsrc[j];
      short hv = bf16_trunc(x);
      hi[j] = hv;
      lo[j] = bf16_trunc(x - bf16_tof(hv));
    }
    *(short8*)&whi[i2 * 8] = *(const short8*)hi;
    *(short8*)&wlo[i2 * 8] = *(const short8*)lo;
  }

  int row0 = pb * 64;
  int w = threadIdx.x >> 6;
  int l = threadIdx.x & 63;
  int m = l & 15;
  int q = l >> 4;

  int arow = row0 + w * 16 + m;
  if (arow >= N_NODES) arow = N_NODES - 1;
  const float* xsrc = h_init + (size_t)arow * IN_DIM + q * 8;

  short8 ahi[4], alo[4];
#pragma unroll
  for (int kc = 0; kc < 4; kc++) {
    float xv[8];
    *(float4*)&xv[0] = *(const float4*)(xsrc + kc * 32);
    *(float4*)&xv[4] = *(const float4*)(xsrc + kc * 32 + 4);
    short hi[8], lo[8];
#pragma unroll
    for (int j = 0; j < 8; j++) {
      short hv = bf16_trunc(xv[j]);
      hi[j] = hv;
      lo[j] = bf16_trunc(xv[j] - bf16_tof(hv));
    }
    ahi[kc] = *(const short8*)hi;
    alo[kc] = *(const short8*)lo;
  }
  __syncthreads();

  f32x4 acc[4] = {{0.f, 0.f, 0.f, 0.f},
                  {0.f, 0.f, 0.f, 0.f},
                  {0.f, 0.f, 0.f, 0.f},
                  {0.f, 0.f, 0.f, 0.f}};

#pragma unroll
  for (int kc = 0; kc < 4; kc++) {
#pragma unroll
    for (int ot = 0; ot < 4; ot++) {
      int base = (((kc << 2) | ot) * 64 + l) * 8;
      short8 bhi = *(const short8*)&whi[base];
      short8 blo = *(const short8*)&wlo[base];
      acc[ot] = __builtin_amdgcn_mfma_f32_16x16x32_bf16(ahi[kc], bhi, acc[ot],
                                                        0, 0, 0);
      acc[ot] = __builtin_amdgcn_mfma_f32_16x16x32_bf16(ahi[kc], blo, acc[ot],
                                                        0, 0, 0);
      acc[ot] = __builtin_amdgcn_mfma_f32_16x16x32_bf16(alo[kc], bhi, acc[ot],
                                                        0, 0, 0);
    }
  }

  float pa[4] = {0.f, 0.f, 0.f, 0.f};
#pragma unroll
  for (int ot = 0; ot < 4; ot++) {
    float aval = a[ot * 16 + m];
#pragma unroll
    for (int r = 0; r < 4; r++) pa[r] += acc[ot][r] * aval;
  }
  int rowb = row0 + w * 16 + q * 4;
#pragma unroll
  for (int r = 0; r < 4; r++) {
    int row = rowb + r;
    if (row < N_NODES) {
#pragma unroll
      for (int ot = 0; ot < 4; ot++) {
        h[(size_t)row * OUT_DIM + ot * 16 + m] = acc[ot][r];
        h16[(size_t)row * OUT_DIM + ot * 16 + m] = __float2half(acc[ot][r]);
      }
    }
  }
#pragma unroll
  for (int r = 0; r < 4; r++) {
    pa[r] += __shfl_xor(pa[r], 1);
    pa[r] += __shfl_xor(pa[r], 2);
    pa[r] += __shfl_xor(pa[r], 4);
    pa[r] += __shfl_xor(pa[r], 8);
  }
  if (m == 0) {
#pragma unroll
    for (int r = 0; r < 4; r++) {
      int row = rowb + r;
      if (row < N_NODES) ha[row] = pa[r];
    }
  }
}

// ---- Fused sort+gather: in-LDS counting sort, then register gather -------
// One block (1024 thr) per 256-node bucket. Sort = R0's verified pattern
// (1 LDS atomic hist + 1 LDS atomic scatter per edge); sorted list stays in
// LDS (no global round-trip). Gather = verified 8-lane-subgroup fma_mix.
__global__ __launch_bounds__(SG_THREADS) void sortgather_kernel(
    const float* __restrict__ h, const __half* __restrict__ h16,
    const float* __restrict__ ha, const int* __restrict__ bucket_cursor,
    const unsigned int* __restrict__ pairs, float* __restrict__ out) {
  __shared__ unsigned int plds[MAXB];  // 18 KB
  __shared__ int2 slds[MAXB];          // 36 KB
  __shared__ float had[256];
  __shared__ int hist[256];
  __shared__ int scn[256];
  __shared__ int cur[256];
  int b = blockIdx.x;
  int t = threadIdx.x;
  int node0 = b << 8;
  int cnt = min(bucket_cursor[b * CUR_STRIDE], MAXB);

  if (t < 256) {
    int node = node0 + t;
    had[t] = (node < N_NODES) ? ha[node] : 0.f;
    hist[t] = 0;
  }
  __syncthreads();
  for (int i = t; i < cnt; i += SG_THREADS) {
    unsigned int p = pairs[(size_t)b * MAXB + i];
    plds[i] = p;
    atomicAdd(&hist[p & 255u], 1);
  }
  __syncthreads();
  int v = (t < 256) ? hist[t] : 0;
  if (t < 256) scn[t] = v;
  __syncthreads();
  for (int off = 1; off < 256; off <<= 1) {
    int u = (t >= off && t < 256) ? scn[t - off] : 0;
    __syncthreads();
    if (t < 256) scn[t] += u;
    __syncthreads();
  }
  if (t < 256) cur[t] = scn[t] - v;  // exclusive
  __syncthreads();
  for (int i = t; i < cnt; i += SG_THREADS) {
    unsigned int p = plds[i];
    int nl = (int)(p & 255u);
    int s = (int)(p >> 8);
    float ex = edge_ex(had[nl] - ha[s]);
    int pos = atomicAdd(&cur[nl], 1);
    slds[pos] = make_int2(s << 7, __float_as_int(ex));  // h16 byte offset
  }
  __syncthreads();

  // ---- gather phase: wave w handles nodes w, w+16, ... (16 each) ----
  int wv = t >> 6;
  int lane = t & 63;
  int g = lane >> 3;  // subgroup 0..7
  int l8 = lane & 7;  // cols [8*l8, 8*l8+8)
  const char* h16b = (const char*)h16;
  const float4* h4 = (const float4*)h;
  float4* o4 = (float4*)out;

  for (int nl = wv; nl < 256; nl += 16) {
    int node = node0 + nl;
    if (node >= N_NODES) break;  // uniform per wave
    int endp = scn[nl];
    int begp = endp - hist[nl];
    float4 hd0 = h4[(size_t)node * (OUT_DIM / 4) + l8 * 2];
    float4 hd1 = h4[(size_t)node * (OUT_DIM / 4) + l8 * 2 + 1];
    float acc[8] = {0.f, 0.f, 0.f, 0.f, 0.f, 0.f, 0.f, 0.f};
    float den = 0.f;
    int last = endp - 1;

    for (int base = begp + g * 4; base < endp; base += 32) {
      int2 e[4];
      float exv[4];
#pragma unroll
      for (int k = 0; k < 4; k++) {
        int i = base + k;
        e[k] = slds[i < endp ? i : last];
        exv[k] = (i < endp) ? __int_as_float(e[k].y) : 0.f;
      }
      uint4 uv[4];
#pragma unroll
      for (int k = 0; k < 4; k++)
        uv[k] = *(const uint4*)(h16b + e[k].x + (l8 << 4));
#pragma unroll
      for (int k = 0; k < 4; k++) {
        union {
          uint4 u;
          __half hh[8];
        } U;
        U.u = uv[k];
        float ex = exv[k];
        den += ex;
#pragma unroll
        for (int j = 0; j < 8; j++)
          acc[j] = fmaf(__half2float(U.hh[j]), ex, acc[j]);  // v_fma_mix_f32
      }
    }

#pragma unroll
    for (int j = 0; j < 8; j++) {
      acc[j] += __shfl_xor(acc[j], 8);
      acc[j] += __shfl_xor(acc[j], 16);
      acc[j] += __shfl_xor(acc[j], 32);
    }
    den += __shfl_xor(den, 8);
    den += __shfl_xor(den, 16);
    den += __shfl_xor(den, 32);

    if (g == 0) {
      bool has = den > 0.f;
      float inv = has ? __builtin_amdgcn_rcpf(den) : 0.f;
      float4 r0, r1;
      r0.x = fmaxf(has ? 2.f * hd0.x - acc[0] * inv : hd0.x, 0.f);
      r0.y = fmaxf(has ? 2.f * hd0.y - acc[1] * inv : hd0.y, 0.f);
      r0.z = fmaxf(has ? 2.f * hd0.z - acc[2] * inv : hd0.z, 0.f);
      r0.w = fmaxf(has ? 2.f * hd0.w - acc[3] * inv : hd0.w, 0.f);
      r1.x = fmaxf(has ? 2.f * hd1.x - acc[4] * inv : hd1.x, 0.f);
      r1.y = fmaxf(has ? 2.f * hd1.y - acc[5] * inv : hd1.y, 0.f);
      r1.z = fmaxf(has ? 2.f * hd1.z - acc[6] * inv : hd1.z, 0.f);
      r1.w = fmaxf(has ? 2.f * hd1.w - acc[7] * inv : hd1.w, 0.f);
      o4[(size_t)node * (OUT_DIM / 4) + l8 * 2] = r0;
      o4[(size_t)node * (OUT_DIM / 4) + l8 * 2 + 1] = r1;
    }
  }
}

extern "C" void kernel_launch(void* const* d_in, const int* in_sizes, int n_in,
                              void* d_out, int out_size, void* d_ws,
                              size_t ws_size, hipStream_t stream) {
  const float* h_init = (const float*)d_in[0];
  const float* W1 = (const float*)d_in[1];
  const float* a = (const float*)d_in[2];
  const int* src = (const int*)d_in[3];
  const int* dst = (const int*)d_in[4];
  float* out = (float*)d_out;

  // workspace layout (~46 MB)
  float* h = (float*)d_ws;                                  // 6.4M floats
  __half* h16 = (__half*)(h + (size_t)N_NODES * OUT_DIM);   // 6.4M halfs
  float* ha = (float*)(h16 + (size_t)N_NODES * OUT_DIM);    // 100K floats
  unsigned int* pairs = (unsigned int*)(ha + N_NODES);      // NBUCK*MAXB u32
  int* bucket_cursor = (int*)(pairs + (size_t)NBUCK * MAXB);  // 391*16

  hipMemsetAsync(bucket_cursor, 0, NBUCK * CUR_STRIDE * sizeof(int), stream);
  fused_pb_kernel<<<PB_GRID, 256, 0, stream>>>(h_init, W1, a, src, dst, h, h16,
                                               ha, bucket_cursor, pairs);
  sortgather_kernel<<<NBUCK, SG_THREADS, 0, stream>>>(h, h16, ha, bucket_cursor,
                                                      pairs, out);
}

// Round 5
// 204.742 us; speedup vs baseline: 4.1223x; 1.0498x over previous
//
#include <hip/hip_runtime.h>
#include <hip/hip_fp16.h>

#define N_NODES 100000
#define N_EDGES 1600000
#define IN_DIM 128
#define OUT_DIM 64

#define PROJ_BLKS 1563  // ceil(N_NODES/64): 64 rows per block (4 waves x 16)

// Buckets of 128 nodes: bucket = dst >> 7.
#define NB2 782        // ceil(N_NODES/128)
#define MAXB2 2560     // Binom(1.6M,128/1e5): mean 2048, sigma 45; +11 sigma
#define CUR_STRIDE 16  // one cursor per 64B line (no cross-XCD false sharing)

#define BIN_NBLK 250
#define BIN_CHUNK 6400   // BIN_NBLK * BIN_CHUNK == N_EDGES
#define BIN_THREADS 1024 // 16 waves/block: latency chains need TLP

#define SG_THREADS 512   // 8 waves; LDS ~33KB -> 4 blocks/CU, 782 co-resident

typedef short short8 __attribute__((ext_vector_type(8)));
typedef float f32x4 __attribute__((ext_vector_type(4)));

__device__ __forceinline__ short bf16_trunc(float x) {
  return (short)(__float_as_uint(x) >> 16);
}
__device__ __forceinline__ float bf16_tof(short s) {
  return __uint_as_float(((unsigned)(unsigned short)s) << 16);
}
__device__ __forceinline__ float edge_ex(float p) {
  float t2 = __expf(2.f * p);
  float th = 1.f - 2.f * __builtin_amdgcn_rcpf(t2 + 1.f);
  return __expf(th);
}

// ---------------- Kernel 1: MFMA projection ----------------
__global__ __launch_bounds__(256) void fat1_kernel(
    const float* __restrict__ h_init, const float* __restrict__ W1,
    const float* __restrict__ a, float* __restrict__ h,
    __half* __restrict__ h16, float* __restrict__ ha) {
  __shared__ short whi[16 * 64 * 8];  // 16 KB
  __shared__ short wlo[16 * 64 * 8];  // 16 KB

  // stage W as bf16 hi/lo B-fragments (frag f=kc*4+ot, B[k][n]=W1[ot*16+n][k])
  for (int idx = threadIdx.x; idx < 16 * 64; idx += 256) {
    int f = idx >> 6;
    int l = idx & 63;
    int kc = f >> 2, ot = f & 3;
    const float* wsrc =
        W1 + (ot * 16 + (l & 15)) * IN_DIM + kc * 32 + (l >> 4) * 8;
    short hi[8], lo[8];
#pragma unroll
    for (int j = 0; j < 8; j++) {
      float x = wsrc[j];
      short hv = bf16_trunc(x);
      hi[j] = hv;
      lo[j] = bf16_trunc(x - bf16_tof(hv));
    }
    *(short8*)&whi[idx * 8] = *(const short8*)hi;
    *(short8*)&wlo[idx * 8] = *(const short8*)lo;
  }

  int row0 = blockIdx.x * 64;
  int w = threadIdx.x >> 6;
  int l = threadIdx.x & 63;
  int m = l & 15;
  int q = l >> 4;

  int arow = row0 + w * 16 + m;
  if (arow >= N_NODES) arow = N_NODES - 1;
  const float* xsrc = h_init + (size_t)arow * IN_DIM + q * 8;

  short8 ahi[4], alo[4];
#pragma unroll
  for (int kc = 0; kc < 4; kc++) {
    float xv[8];
    *(float4*)&xv[0] = *(const float4*)(xsrc + kc * 32);
    *(float4*)&xv[4] = *(const float4*)(xsrc + kc * 32 + 4);
    short hi[8], lo[8];
#pragma unroll
    for (int j = 0; j < 8; j++) {
      short hv = bf16_trunc(xv[j]);
      hi[j] = hv;
      lo[j] = bf16_trunc(xv[j] - bf16_tof(hv));
    }
    ahi[kc] = *(const short8*)hi;
    alo[kc] = *(const short8*)lo;
  }
  __syncthreads();

  f32x4 acc[4] = {{0.f, 0.f, 0.f, 0.f},
                  {0.f, 0.f, 0.f, 0.f},
                  {0.f, 0.f, 0.f, 0.f},
                  {0.f, 0.f, 0.f, 0.f}};

#pragma unroll
  for (int kc = 0; kc < 4; kc++) {
#pragma unroll
    for (int ot = 0; ot < 4; ot++) {
      int base = (((kc << 2) | ot) * 64 + l) * 8;
      short8 bhi = *(const short8*)&whi[base];
      short8 blo = *(const short8*)&wlo[base];
      acc[ot] = __builtin_amdgcn_mfma_f32_16x16x32_bf16(ahi[kc], bhi, acc[ot],
                                                        0, 0, 0);
      acc[ot] = __builtin_amdgcn_mfma_f32_16x16x32_bf16(ahi[kc], blo, acc[ot],
                                                        0, 0, 0);
      acc[ot] = __builtin_amdgcn_mfma_f32_16x16x32_bf16(alo[kc], bhi, acc[ot],
                                                        0, 0, 0);
    }
  }

  float pa[4] = {0.f, 0.f, 0.f, 0.f};
#pragma unroll
  for (int ot = 0; ot < 4; ot++) {
    float aval = a[ot * 16 + m];
#pragma unroll
    for (int r = 0; r < 4; r++) pa[r] += acc[ot][r] * aval;
  }
  int rowb = row0 + w * 16 + q * 4;
#pragma unroll
  for (int r = 0; r < 4; r++) {
    int row = rowb + r;
    if (row < N_NODES) {
#pragma unroll
      for (int ot = 0; ot < 4; ot++) {
        h[(size_t)row * OUT_DIM + ot * 16 + m] = acc[ot][r];
        h16[(size_t)row * OUT_DIM + ot * 16 + m] = __float2half(acc[ot][r]);
      }
    }
  }
#pragma unroll
  for (int r = 0; r < 4; r++) {
    pa[r] += __shfl_xor(pa[r], 1);
    pa[r] += __shfl_xor(pa[r], 2);
    pa[r] += __shfl_xor(pa[r], 4);
    pa[r] += __shfl_xor(pa[r], 8);
  }
  if (m == 0) {
#pragma unroll
    for (int r = 0; r < 4; r++) {
      int row = rowb + r;
      if (row < N_NODES) ha[row] = pa[r];
    }
  }
}

// ------- Partition into static 128-node bucket regions ----------------
// pairs[pos] = (src << 7) | (dst & 127); region base b*MAXB2 static;
// bucket_cursor holds relative counts (zeroed by hipMemsetAsync).
// 6400-edge chunks keep per-(block,bucket) write runs ~8 edges (33B);
// 1024 threads give the latency chains 4x the TLP of the 256-thr version.
__global__ __launch_bounds__(BIN_THREADS) void bin_scatter_kernel(
    const int* __restrict__ src, const int* __restrict__ dst,
    int* __restrict__ bucket_cursor, unsigned int* __restrict__ pairs) {
  __shared__ int hst[NB2];
  __shared__ int cur[NB2];
  __shared__ int dlds[BIN_CHUNK];  // 25.6 KB dst cache
  int t = threadIdx.x;
  for (int i = t; i < NB2; i += BIN_THREADS) hst[i] = 0;
  __syncthreads();
  int beg = blockIdx.x * BIN_CHUNK;
  for (int e = t; e < BIN_CHUNK; e += BIN_THREADS) {
    int d = dst[beg + e];
    dlds[e] = d;
    atomicAdd(&hst[d >> 7], 1);
  }
  __syncthreads();
  for (int i = t; i < NB2; i += BIN_THREADS) {
    int c = hst[i];
    cur[i] =
        (c > 0) ? atomicAdd(&bucket_cursor[i * CUR_STRIDE], c) + i * MAXB2 : 0;
  }
  __syncthreads();
  for (int e = t; e < BIN_CHUNK; e += BIN_THREADS) {
    int d = dlds[e];
    int pos = atomicAdd(&cur[d >> 7], 1);
    pairs[pos] = ((unsigned int)src[beg + e] << 7) | (unsigned int)(d & 127);
  }
}

// ---- Fused sort+gather: in-LDS counting sort, then register gather -------
// One block (512 thr) per 128-node bucket; 782 blocks x 4/CU = all
// co-resident (no load-imbalance tail). Sorted list never touches global.
// Gather: 8-lane subgroup per edge, stride-8 interleave so all 8 subgroups
// are active for deg>=8 (old 4-blocked mapping idled half the wave at deg 16).
__global__ __launch_bounds__(SG_THREADS) void sortgather_kernel(
    const float* __restrict__ h, const __half* __restrict__ h16,
    const float* __restrict__ ha, const int* __restrict__ bucket_cursor,
    const unsigned int* __restrict__ pairs, float* __restrict__ out) {
  __shared__ unsigned int plds[MAXB2];  // 10.2 KB
  __shared__ int2 slds[MAXB2];          // 20.5 KB
  __shared__ float had[128];
  __shared__ int hist[128];
  __shared__ int scn[128];
  __shared__ int cur[128];
  int b = blockIdx.x;
  int t = threadIdx.x;
  int node0 = b << 7;
  int cnt = min(bucket_cursor[b * CUR_STRIDE], MAXB2);

  if (t < 128) {
    int node = node0 + t;
    had[t] = (node < N_NODES) ? ha[node] : 0.f;
    hist[t] = 0;
  }
  __syncthreads();
  for (int i = t; i < cnt; i += SG_THREADS) {
    unsigned int p = pairs[(size_t)b * MAXB2 + i];
    plds[i] = p;
    atomicAdd(&hist[p & 127u], 1);
  }
  __syncthreads();
  int v = (t < 128) ? hist[t] : 0;
  if (t < 128) scn[t] = v;
  __syncthreads();
  for (int off = 1; off < 128; off <<= 1) {
    int u = (t >= off && t < 128) ? scn[t - off] : 0;
    __syncthreads();
    if (t < 128) scn[t] += u;
    __syncthreads();
  }
  if (t < 128) cur[t] = scn[t] - v;  // exclusive prefix
  __syncthreads();
  for (int i = t; i < cnt; i += SG_THREADS) {
    unsigned int p = plds[i];
    int nl = (int)(p & 127u);
    int sb = (int)(p & 0xFFFFFF80u);  // src << 7 == h16 row byte offset
    float ex = edge_ex(had[nl] - ha[sb >> 7]);
    int pos = atomicAdd(&cur[nl], 1);
    slds[pos] = make_int2(sb, __float_as_int(ex));
  }
  __syncthreads();

  // ---- gather phase: wave wv handles nodes wv, wv+8, ... (16 each) ----
  int wv = t >> 6;
  int lane = t & 63;
  int g = lane >> 3;  // subgroup 0..7
  int l8 = lane & 7;  // cols [8*l8, 8*l8+8)
  const char* h16b = (const char*)h16;
  const float4* h4 = (const float4*)h;
  float4* o4 = (float4*)out;

  for (int nl = wv; nl < 128; nl += 8) {
    int node = node0 + nl;
    if (node >= N_NODES) break;  // uniform per wave
    int endp = scn[nl];
    int begp = endp - hist[nl];
    float4 hd0 = h4[(size_t)node * (OUT_DIM / 4) + l8 * 2];
    float4 hd1 = h4[(size_t)node * (OUT_DIM / 4) + l8 * 2 + 1];
    float acc[8] = {0.f, 0.f, 0.f, 0.f, 0.f, 0.f, 0.f, 0.f};
    float den = 0.f;
    int last = endp - 1;

    // subgroup g covers edges begp+g, +8, +16, ... (stride-8 interleave)
    for (int i0 = begp + g; i0 < endp; i0 += 32) {
      int2 e[4];
      float exv[4];
#pragma unroll
      for (int k = 0; k < 4; k++) {
        int i = i0 + k * 8;
        e[k] = slds[i < endp ? i : last];
        exv[k] = (i < endp) ? __int_as_float(e[k].y) : 0.f;
      }
      uint4 uv[4];
#pragma unroll
      for (int k = 0; k < 4; k++)
        uv[k] = *(const uint4*)(h16b + e[k].x + (l8 << 4));
#pragma unroll
      for (int k = 0; k < 4; k++) {
        union {
          uint4 u;
          __half hh[8];
        } U;
        U.u = uv[k];
        float ex = exv[k];
        den += ex;
#pragma unroll
        for (int j = 0; j < 8; j++)
          acc[j] = fmaf(__half2float(U.hh[j]), ex, acc[j]);  // v_fma_mix_f32
      }
    }

#pragma unroll
    for (int j = 0; j < 8; j++) {
      acc[j] += __shfl_xor(acc[j], 8);
      acc[j] += __shfl_xor(acc[j], 16);
      acc[j] += __shfl_xor(acc[j], 32);
    }
    den += __shfl_xor(den, 8);
    den += __shfl_xor(den, 16);
    den += __shfl_xor(den, 32);

    if (g == 0) {
      bool has = den > 0.f;
      float inv = has ? __builtin_amdgcn_rcpf(den) : 0.f;
      float4 r0, r1;
      r0.x = fmaxf(has ? 2.f * hd0.x - acc[0] * inv : hd0.x, 0.f);
      r0.y = fmaxf(has ? 2.f * hd0.y - acc[1] * inv : hd0.y, 0.f);
      r0.z = fmaxf(has ? 2.f * hd0.z - acc[2] * inv : hd0.z, 0.f);
      r0.w = fmaxf(has ? 2.f * hd0.w - acc[3] * inv : hd0.w, 0.f);
      r1.x = fmaxf(has ? 2.f * hd1.x - acc[4] * inv : hd1.x, 0.f);
      r1.y = fmaxf(has ? 2.f * hd1.y - acc[5] * inv : hd1.y, 0.f);
      r1.z = fmaxf(has ? 2.f * hd1.z - acc[6] * inv : hd1.z, 0.f);
      r1.w = fmaxf(has ? 2.f * hd1.w - acc[7] * inv : hd1.w, 0.f);
      o4[(size_t)node * (OUT_DIM / 4) + l8 * 2] = r0;
      o4[(size_t)node * (OUT_DIM / 4) + l8 * 2 + 1] = r1;
    }
  }
}

extern "C" void kernel_launch(void* const* d_in, const int* in_sizes, int n_in,
                              void* d_out, int out_size, void* d_ws,
                              size_t ws_size, hipStream_t stream) {
  const float* h_init = (const float*)d_in[0];
  const float* W1 = (const float*)d_in[1];
  const float* a = (const float*)d_in[2];
  const int* src = (const int*)d_in[3];
  const int* dst = (const int*)d_in[4];
  float* out = (float*)d_out;

  // workspace layout (~48 MB)
  float* h = (float*)d_ws;                                   // 6.4M floats
  __half* h16 = (__half*)(h + (size_t)N_NODES * OUT_DIM);    // 6.4M halfs
  float* ha = (float*)(h16 + (size_t)N_NODES * OUT_DIM);     // 100K floats
  unsigned int* pairs = (unsigned int*)(ha + N_NODES);       // NB2*MAXB2 u32
  int* bucket_cursor = (int*)(pairs + (size_t)NB2 * MAXB2);  // 782*16

  hipMemsetAsync(bucket_cursor, 0, NB2 * CUR_STRIDE * sizeof(int), stream);
  fat1_kernel<<<PROJ_BLKS, 256, 0, stream>>>(h_init, W1, a, h, h16, ha);
  bin_scatter_kernel<<<BIN_NBLK, BIN_THREADS, 0, stream>>>(src, dst,
                                                           bucket_cursor,
                                                           pairs);
  sortgather_kernel<<<NB2, SG_THREADS, 0, stream>>>(h, h16, ha, bucket_cursor,
                                                    pairs, out);
}